// Round 1
// baseline (315.742 us; speedup 1.0000x reference)
//
#include <hip/hip_runtime.h>
#include <hip/hip_bf16.h>
#include <stdint.h>

#define B_ 2
#define S_ 2048
#define D_ 1024
#define H_ 16
#define HD_ 64
#define SCALE_ 0.125f

typedef __attribute__((ext_vector_type(8))) short bfx8;
typedef __attribute__((ext_vector_type(4))) float f32x4;

// async global->LDS, 16B per lane; LDS dest = wave-uniform base + lane*16
__device__ __forceinline__ void gld_lds16(const void* g, void* l) {
    __builtin_amdgcn_global_load_lds(
        (const __attribute__((address_space(1))) void*)g,
        (__attribute__((address_space(3))) void*)l, 16, 0, 0);
}

// ---------------------------------------------------------------------------
// f32 -> bf16 cast of the three input activations
__global__ __launch_bounds__(256) void cast3_bf16(
    const float* __restrict__ a, const float* __restrict__ b, const float* __restrict__ c,
    __hip_bfloat16* __restrict__ oa, __hip_bfloat16* __restrict__ ob, __hip_bfloat16* __restrict__ oc)
{
    const float* src = blockIdx.y == 0 ? a : blockIdx.y == 1 ? b : c;
    __hip_bfloat16* dst = blockIdx.y == 0 ? oa : blockIdx.y == 1 ? ob : oc;
    const size_t i = ((size_t)blockIdx.x * 256 + threadIdx.x) * 4;
    float4 v = *(const float4*)(src + i);
    ushort4 u;
    __hip_bfloat16 t;
    t = __float2bfloat16(v.x); u.x = *(unsigned short*)&t;
    t = __float2bfloat16(v.y); u.y = *(unsigned short*)&t;
    t = __float2bfloat16(v.z); u.z = *(unsigned short*)&t;
    t = __float2bfloat16(v.w); u.w = *(unsigned short*)&t;
    *(ushort4*)(dst + i) = u;
}

// transpose + cast the four 1024x1024 weight matrices: W[K][N] -> Wt[N][K] bf16
__global__ __launch_bounds__(256) void transpose_cast_w(
    const float* __restrict__ w0, const float* __restrict__ w1,
    const float* __restrict__ w2, const float* __restrict__ w3,
    __hip_bfloat16* __restrict__ o0, __hip_bfloat16* __restrict__ o1,
    __hip_bfloat16* __restrict__ o2, __hip_bfloat16* __restrict__ o3)
{
    __shared__ float t[32][33];
    const int z = blockIdx.z;
    const float* W = z == 0 ? w0 : z == 1 ? w1 : z == 2 ? w2 : w3;
    __hip_bfloat16* Wt = z == 0 ? o0 : z == 1 ? o1 : z == 2 ? o2 : o3;
    const int bx = blockIdx.x * 32, by = blockIdx.y * 32;
    const int x = threadIdx.x, y = threadIdx.y;
#pragma unroll
    for (int i = 0; i < 32; i += 8)
        t[y + i][x] = W[(size_t)(by + y + i) * 1024 + bx + x];
    __syncthreads();
#pragma unroll
    for (int i = 0; i < 32; i += 8)
        Wt[(size_t)(bx + y + i) * 1024 + by + x] = __float2bfloat16(t[x][y + i]);
}

// ---------------------------------------------------------------------------
// bf16 GEMM: C[M=4096,N=1024] = A[M,K=1024] @ Bt[N,K]^T + bias
// mode 0: write bf16 at [B,H,S,HD]   (q,k projections)
// mode 1: write bf16 at [B,H,HD,S]   (v projection, transposed for PV)
// mode 2: write f32 row-major [M,N]  (final output)
__global__ __launch_bounds__(256, 2) void gemm128(
    const __hip_bfloat16* __restrict__ A,
    const __hip_bfloat16* __restrict__ Bt,
    const float* __restrict__ bias,
    void* __restrict__ Cout, int mode)
{
    constexpr int K = 1024, N = 1024;
    __shared__ __align__(16) __hip_bfloat16 As[128 * 32];
    __shared__ __align__(16) __hip_bfloat16 Bs[128 * 32];
    const int tid = threadIdx.x;
    const int wid = tid >> 6, lane = tid & 63;
    const int wm = (wid >> 1) * 64, wn = (wid & 1) * 64;
    const int bm = blockIdx.x * 128, bn = blockIdx.y * 128;

    f32x4 acc[4][4] = {};

    const int srow = lane >> 2;          // 0..15 (row within 16-row chunk)
    const int scol = (lane & 3) * 8;     // elem col within 32-elem row

    for (int kt = 0; kt < K / 32; ++kt) {
        __syncthreads();
#pragma unroll
        for (int i = 0; i < 2; ++i) {
            const int rb = wid * 32 + i * 16;
            gld_lds16(A  + (size_t)(bm + rb + srow) * K + kt * 32 + scol, (char*)As + rb * 64);
            gld_lds16(Bt + (size_t)(bn + rb + srow) * K + kt * 32 + scol, (char*)Bs + rb * 64);
        }
        __syncthreads();
        bfx8 af[4], bf[4];
#pragma unroll
        for (int m = 0; m < 4; ++m)
            af[m] = *(const bfx8*)((const char*)As + (wm + m * 16 + (lane & 15)) * 64 + (lane >> 4) * 16);
#pragma unroll
        for (int n = 0; n < 4; ++n)
            bf[n] = *(const bfx8*)((const char*)Bs + (wn + n * 16 + (lane & 15)) * 64 + (lane >> 4) * 16);
#pragma unroll
        for (int m = 0; m < 4; ++m)
#pragma unroll
            for (int n = 0; n < 4; ++n)
                acc[m][n] = __builtin_amdgcn_mfma_f32_16x16x32_bf16(af[m], bf[n], acc[m][n], 0, 0, 0);
    }

#pragma unroll
    for (int m = 0; m < 4; ++m) {
        const int row0 = bm + wm + m * 16 + ((lane >> 4) << 2);
#pragma unroll
        for (int n = 0; n < 4; ++n) {
            const int col = bn + wn + n * 16 + (lane & 15);
            const float bv = bias[col];
#pragma unroll
            for (int r = 0; r < 4; ++r) {
                const int i = row0 + r;
                const float v = acc[m][n][r] + bv;
                if (mode == 2) {
                    ((float*)Cout)[(size_t)i * N + col] = v;
                } else {
                    const int b = i >> 11, s = i & 2047, h = col >> 6, d = col & 63;
                    const size_t off = (mode == 0)
                        ? ((((size_t)b * H_ + h) * S_ + s) * HD_ + d)
                        : ((((size_t)b * H_ + h) * HD_ + d) * S_ + s);
                    ((__hip_bfloat16*)Cout)[off] = __float2bfloat16(v);
                }
            }
        }
    }
}

// ---------------------------------------------------------------------------
// Fused attention: per (b,h) x 128-q-row tile. Two-pass flash:
//   pass1: l = sum_k exp(s*scale)      (scores bounded, no max-subtraction)
//   pass2: recompute s, w = exp(s*scale)/l -> write attn weights (f32, d_out)
//          and accumulate O += P @ V via LDS-transposed P.
// K/V/P LDS tiles are XOR-swizzled (byte ^= (row&7)<<4) to kill the
// 128B-row-stride bank conflict; swizzle is applied on the *global source*
// address for global_load_lds (linear LDS dest) and on every LDS read.
__global__ __launch_bounds__(256, 2) void attn_fused(
    const __hip_bfloat16* __restrict__ qb,   // [B,H,S,64]
    const __hip_bfloat16* __restrict__ kb,   // [B,H,S,64]
    const __hip_bfloat16* __restrict__ vt,   // [B,H,64,S]
    float* __restrict__ attnw,               // [B,H,S,S]
    __hip_bfloat16* __restrict__ aout)       // [B,S,H*64]
{
    __shared__ __align__(16) __hip_bfloat16 ks_[64 * 64];
    __shared__ __align__(16) __hip_bfloat16 vs_[64 * 64];
    __shared__ __align__(16) __hip_bfloat16 ps_[128 * 64];
    const int bh = blockIdx.y;               // b*16+h
    const int qt = blockIdx.x;               // 0..15
    const int tid = threadIdx.x, wid = tid >> 6, lane = tid & 63;
    const int qrow0 = qt * 128 + wid * 32;   // wave's first q row (s index)

    // Q fragments held in registers: rows qrow0 + rf*16 + (lane&15)
    bfx8 qf[2][2];
#pragma unroll
    for (int rf = 0; rf < 2; ++rf)
#pragma unroll
        for (int kx = 0; kx < 2; ++kx)
            qf[rf][kx] = *(const bfx8*)(qb + ((size_t)bh * S_ + qrow0 + rf * 16 + (lane & 15)) * HD_
                                         + kx * 32 + (lane >> 4) * 8);

    const int sr = lane >> 3;   // row within 8-row staging chunk
    const int sc = lane & 7;    // 16B unit within 128B row

    // ---------------- pass 1: denominators ----------------
    float lsum[2][4] = {};
    for (int kt = 0; kt < 32; ++kt) {
        __syncthreads();
#pragma unroll
        for (int i = 0; i < 2; ++i) {
            const int rb = wid * 16 + i * 8;
            const int row = rb + sr;
            const int colb = (sc * 16) ^ ((row & 7) << 4);
            gld_lds16((const char*)kb + ((size_t)bh * S_ + kt * 64 + row) * 128 + colb,
                      (char*)ks_ + rb * 128);
        }
        __syncthreads();
        f32x4 c[2][4] = {};
#pragma unroll
        for (int kx = 0; kx < 2; ++kx) {
            bfx8 bfv[4];
#pragma unroll
            for (int cf = 0; cf < 4; ++cf) {
                const int row = cf * 16 + (lane & 15);
                bfv[cf] = *(const bfx8*)((const char*)ks_ + row * 128
                                          + ((kx * 64 + (lane >> 4) * 16) ^ ((row & 7) << 4)));
            }
#pragma unroll
            for (int rf = 0; rf < 2; ++rf)
#pragma unroll
                for (int cf = 0; cf < 4; ++cf)
                    c[rf][cf] = __builtin_amdgcn_mfma_f32_16x16x32_bf16(qf[rf][kx], bfv[cf], c[rf][cf], 0, 0, 0);
        }
#pragma unroll
        for (int rf = 0; rf < 2; ++rf)
#pragma unroll
            for (int r = 0; r < 4; ++r) {
                float s = 0.f;
#pragma unroll
                for (int cf = 0; cf < 4; ++cf) s += __expf(c[rf][cf][r] * SCALE_);
                s += __shfl_xor(s, 1); s += __shfl_xor(s, 2);
                s += __shfl_xor(s, 4); s += __shfl_xor(s, 8);
                lsum[rf][r] += s;
            }
    }
    float linv[2][4];
#pragma unroll
    for (int rf = 0; rf < 2; ++rf)
#pragma unroll
        for (int r = 0; r < 4; ++r) linv[rf][r] = 1.f / lsum[rf][r];

    // ---------------- pass 2: weights + PV ----------------
    f32x4 o[2][4] = {};
    for (int kt = 0; kt < 32; ++kt) {
        __syncthreads();
#pragma unroll
        for (int i = 0; i < 2; ++i) {
            const int rb = wid * 16 + i * 8;
            const int row = rb + sr;
            const int colb = (sc * 16) ^ ((row & 7) << 4);
            gld_lds16((const char*)kb + ((size_t)bh * S_ + kt * 64 + row) * 128 + colb,
                      (char*)ks_ + rb * 128);
            gld_lds16((const char*)vt + (((size_t)bh * HD_ + row) * S_ + kt * 64) * 2 + colb,
                      (char*)vs_ + rb * 128);
        }
        __syncthreads();
        f32x4 c[2][4] = {};
#pragma unroll
        for (int kx = 0; kx < 2; ++kx) {
            bfx8 bfv[4];
#pragma unroll
            for (int cf = 0; cf < 4; ++cf) {
                const int row = cf * 16 + (lane & 15);
                bfv[cf] = *(const bfx8*)((const char*)ks_ + row * 128
                                          + ((kx * 64 + (lane >> 4) * 16) ^ ((row & 7) << 4)));
            }
#pragma unroll
            for (int rf = 0; rf < 2; ++rf)
#pragma unroll
                for (int cf = 0; cf < 4; ++cf)
                    c[rf][cf] = __builtin_amdgcn_mfma_f32_16x16x32_bf16(qf[rf][kx], bfv[cf], c[rf][cf], 0, 0, 0);
        }
        // normalized weights -> global + swizzled LDS (bf16) for the PV MFMA
#pragma unroll
        for (int rf = 0; rf < 2; ++rf)
#pragma unroll
            for (int r = 0; r < 4; ++r) {
                const int qrow = qrow0 + rf * 16 + ((lane >> 4) << 2) + r;
                float* wout = attnw + ((size_t)bh * S_ + qrow) * S_ + kt * 64;
                const int prow = wid * 32 + rf * 16 + ((lane >> 4) << 2) + r;
#pragma unroll
                for (int cf = 0; cf < 4; ++cf) {
                    const float w = __expf(c[rf][cf][r] * SCALE_) * linv[rf][r];
                    wout[cf * 16 + (lane & 15)] = w;
                    const int pcolb = ((cf * 16 + (lane & 15)) * 2) ^ ((prow & 7) << 4);
                    *(__hip_bfloat16*)((char*)ps_ + prow * 128 + pcolb) = __float2bfloat16(w);
                }
            }
        __syncthreads();
        // O += P @ V
#pragma unroll
        for (int kx = 0; kx < 2; ++kx) {
            bfx8 pf[2], vf[4];
#pragma unroll
            for (int rf = 0; rf < 2; ++rf) {
                const int prow = wid * 32 + rf * 16 + (lane & 15);
                pf[rf] = *(const bfx8*)((const char*)ps_ + prow * 128
                                         + ((kx * 64 + (lane >> 4) * 16) ^ ((prow & 7) << 4)));
            }
#pragma unroll
            for (int df = 0; df < 4; ++df) {
                const int vrow = df * 16 + (lane & 15);
                vf[df] = *(const bfx8*)((const char*)vs_ + vrow * 128
                                         + ((kx * 64 + (lane >> 4) * 16) ^ ((vrow & 7) << 4)));
            }
#pragma unroll
            for (int rf = 0; rf < 2; ++rf)
#pragma unroll
                for (int df = 0; df < 4; ++df)
                    o[rf][df] = __builtin_amdgcn_mfma_f32_16x16x32_bf16(pf[rf], vf[df], o[rf][df], 0, 0, 0);
        }
    }

    // write attention output (bf16) at [B,S,H*64] for the final GEMM
    const int b = bh >> 4, h = bh & 15;
#pragma unroll
    for (int rf = 0; rf < 2; ++rf)
#pragma unroll
        for (int r = 0; r < 4; ++r) {
            const int s = qrow0 + rf * 16 + ((lane >> 4) << 2) + r;
#pragma unroll
            for (int df = 0; df < 4; ++df) {
                const int d = df * 16 + (lane & 15);
                aout[((size_t)b * S_ + s) * D_ + h * HD_ + d] = __float2bfloat16(o[rf][df][r]);
            }
        }
}

// ---------------------------------------------------------------------------
extern "C" void kernel_launch(void* const* d_in, const int* in_sizes, int n_in,
                              void* d_out, int out_size, void* d_ws, size_t ws_size,
                              hipStream_t stream)
{
    (void)in_sizes; (void)n_in; (void)out_size; (void)ws_size;
    const float* query = (const float*)d_in[0];
    const float* key_  = (const float*)d_in[1];
    const float* value = (const float*)d_in[2];
    const float* Wq = (const float*)d_in[3];
    const float* bq = (const float*)d_in[4];
    const float* Wk = (const float*)d_in[5];
    const float* bk = (const float*)d_in[6];
    const float* Wv = (const float*)d_in[7];
    const float* bv = (const float*)d_in[8];
    const float* Wo = (const float*)d_in[9];
    const float* bo = (const float*)d_in[10];

    char* ws = (char*)d_ws;
    const size_t MB = 1u << 20;
    __hip_bfloat16* xq   = (__hip_bfloat16*)(ws + 0 * MB);
    __hip_bfloat16* xk   = (__hip_bfloat16*)(ws + 8 * MB);
    __hip_bfloat16* xv   = (__hip_bfloat16*)(ws + 16 * MB);
    __hip_bfloat16* Wqt  = (__hip_bfloat16*)(ws + 24 * MB);
    __hip_bfloat16* Wkt  = (__hip_bfloat16*)(ws + 26 * MB);
    __hip_bfloat16* Wvt  = (__hip_bfloat16*)(ws + 28 * MB);
    __hip_bfloat16* Wot  = (__hip_bfloat16*)(ws + 30 * MB);
    __hip_bfloat16* qb   = (__hip_bfloat16*)(ws + 32 * MB);
    __hip_bfloat16* kbuf = (__hip_bfloat16*)(ws + 40 * MB);
    __hip_bfloat16* vtb  = (__hip_bfloat16*)(ws + 48 * MB);
    __hip_bfloat16* aout = (__hip_bfloat16*)(ws + 56 * MB);

    float* outp  = (float*)d_out;
    float* attnw = outp + (size_t)B_ * S_ * D_;

    cast3_bf16<<<dim3(4096, 3), 256, 0, stream>>>(query, key_, value, xq, xk, xv);
    transpose_cast_w<<<dim3(32, 32, 4), dim3(32, 8), 0, stream>>>(Wq, Wk, Wv, Wo, Wqt, Wkt, Wvt, Wot);
    gemm128<<<dim3(32, 8), 256, 0, stream>>>(xq, Wqt, bq, qb, 0);
    gemm128<<<dim3(32, 8), 256, 0, stream>>>(xk, Wkt, bk, kbuf, 0);
    gemm128<<<dim3(32, 8), 256, 0, stream>>>(xv, Wvt, bv, vtb, 1);
    attn_fused<<<dim3(16, 32), 256, 0, stream>>>(qb, kbuf, vtb, attnw, aout);
    gemm128<<<dim3(32, 8), 256, 0, stream>>>(aout, Wot, bo, (void*)outp, 2);
}

// Round 2
// 297.619 us; speedup vs baseline: 1.0609x; 1.0609x over previous
//
#include <hip/hip_runtime.h>
#include <hip/hip_bf16.h>
#include <stdint.h>

#define B_ 2
#define S_ 2048
#define D_ 1024
#define H_ 16
#define HD_ 64
#define SCALE_ 0.125f

typedef __attribute__((ext_vector_type(8))) short bfx8;
typedef __attribute__((ext_vector_type(4))) float f32x4;

// async global->LDS, 16B per lane; LDS dest = wave-uniform base + lane*16
__device__ __forceinline__ void gld_lds16(const void* g, void* l) {
    __builtin_amdgcn_global_load_lds(
        (const __attribute__((address_space(1))) void*)g,
        (__attribute__((address_space(3))) void*)l, 16, 0, 0);
}

// ---------------------------------------------------------------------------
// f32 -> bf16 cast of the three input activations
__global__ __launch_bounds__(256) void cast3_bf16(
    const float* __restrict__ a, const float* __restrict__ b, const float* __restrict__ c,
    __hip_bfloat16* __restrict__ oa, __hip_bfloat16* __restrict__ ob, __hip_bfloat16* __restrict__ oc)
{
    const float* src = blockIdx.y == 0 ? a : blockIdx.y == 1 ? b : c;
    __hip_bfloat16* dst = blockIdx.y == 0 ? oa : blockIdx.y == 1 ? ob : oc;
    const size_t i = ((size_t)blockIdx.x * 256 + threadIdx.x) * 4;
    float4 v = *(const float4*)(src + i);
    ushort4 u;
    __hip_bfloat16 t;
    t = __float2bfloat16(v.x); u.x = *(unsigned short*)&t;
    t = __float2bfloat16(v.y); u.y = *(unsigned short*)&t;
    t = __float2bfloat16(v.z); u.z = *(unsigned short*)&t;
    t = __float2bfloat16(v.w); u.w = *(unsigned short*)&t;
    *(ushort4*)(dst + i) = u;
}

// transpose + cast the four 1024x1024 weight matrices: W[K][N] -> Wt[N][K] bf16
__global__ __launch_bounds__(256) void transpose_cast_w(
    const float* __restrict__ w0, const float* __restrict__ w1,
    const float* __restrict__ w2, const float* __restrict__ w3,
    __hip_bfloat16* __restrict__ o0, __hip_bfloat16* __restrict__ o1,
    __hip_bfloat16* __restrict__ o2, __hip_bfloat16* __restrict__ o3)
{
    __shared__ float t[32][33];
    const int z = blockIdx.z;
    const float* W = z == 0 ? w0 : z == 1 ? w1 : z == 2 ? w2 : w3;
    __hip_bfloat16* Wt = z == 0 ? o0 : z == 1 ? o1 : z == 2 ? o2 : o3;
    const int bx = blockIdx.x * 32, by = blockIdx.y * 32;
    const int x = threadIdx.x, y = threadIdx.y;
#pragma unroll
    for (int i = 0; i < 32; i += 8)
        t[y + i][x] = W[(size_t)(by + y + i) * 1024 + bx + x];
    __syncthreads();
#pragma unroll
    for (int i = 0; i < 32; i += 8)
        Wt[(size_t)(bx + y + i) * 1024 + by + x] = __float2bfloat16(t[x][y + i]);
}

// ---------------------------------------------------------------------------
// bf16 GEMM body: C[128x128 tile of M=4096,N=1024] = A[M,1024] @ Bt[N,1024]^T + bias
// 2-phase double-buffered global_load_lds staging (T3-lite).
// mode 0: write bf16 at [B,H,S,HD]; mode 1: bf16 at [B,H,HD,S]; mode 2: f32 [M,N]
__device__ __forceinline__ void gemm_body(
    const __hip_bfloat16* __restrict__ A,
    const __hip_bfloat16* __restrict__ Bt,
    const float* __restrict__ bias,
    void* __restrict__ Cout, int mode,
    __hip_bfloat16 (*As)[128 * 32], __hip_bfloat16 (*Bs)[128 * 32],
    int bm, int bn)
{
    constexpr int K = 1024, N = 1024;
    const int tid = threadIdx.x;
    const int wid = tid >> 6, lane = tid & 63;
    const int wm = (wid >> 1) * 64, wn = (wid & 1) * 64;

    f32x4 acc[4][4] = {};

    const int srow = lane >> 2;          // 0..15 (row within 16-row chunk)
    const int scol = (lane & 3) * 8;     // elem col within 32-elem row

    auto stage = [&](int kt, int buf) {
#pragma unroll
        for (int i = 0; i < 2; ++i) {
            const int rb = wid * 32 + i * 16;
            gld_lds16(A  + (size_t)(bm + rb + srow) * K + kt * 32 + scol, (char*)As[buf] + rb * 64);
            gld_lds16(Bt + (size_t)(bn + rb + srow) * K + kt * 32 + scol, (char*)Bs[buf] + rb * 64);
        }
    };

    stage(0, 0);
    __syncthreads();

    for (int kt = 0; kt < K / 32; ++kt) {
        const int cur = kt & 1;
        if (kt < K / 32 - 1) stage(kt + 1, cur ^ 1);
        bfx8 af[4], bf[4];
#pragma unroll
        for (int m = 0; m < 4; ++m)
            af[m] = *(const bfx8*)((const char*)As[cur] + (wm + m * 16 + (lane & 15)) * 64 + (lane >> 4) * 16);
#pragma unroll
        for (int n = 0; n < 4; ++n)
            bf[n] = *(const bfx8*)((const char*)Bs[cur] + (wn + n * 16 + (lane & 15)) * 64 + (lane >> 4) * 16);
#pragma unroll
        for (int m = 0; m < 4; ++m)
#pragma unroll
            for (int n = 0; n < 4; ++n)
                acc[m][n] = __builtin_amdgcn_mfma_f32_16x16x32_bf16(af[m], bf[n], acc[m][n], 0, 0, 0);
        __syncthreads();
    }

#pragma unroll
    for (int m = 0; m < 4; ++m) {
        const int row0 = bm + wm + m * 16 + ((lane >> 4) << 2);
#pragma unroll
        for (int n = 0; n < 4; ++n) {
            const int col = bn + wn + n * 16 + (lane & 15);
            const float bv = bias[col];
#pragma unroll
            for (int r = 0; r < 4; ++r) {
                const int i = row0 + r;
                const float v = acc[m][n][r] + bv;
                if (mode == 2) {
                    ((float*)Cout)[(size_t)i * N + col] = v;
                } else {
                    const int b = i >> 11, s = i & 2047, h = col >> 6, d = col & 63;
                    const size_t off = (mode == 0)
                        ? ((((size_t)b * H_ + h) * S_ + s) * HD_ + d)
                        : ((((size_t)b * H_ + h) * HD_ + d) * S_ + s);
                    ((__hip_bfloat16*)Cout)[off] = __float2bfloat16(v);
                }
            }
        }
    }
}

// fused Q/K/V projections: one launch, blockIdx.z selects the GEMM (3 blocks/CU)
__global__ __launch_bounds__(256, 2) void gemm_qkv(
    const __hip_bfloat16* __restrict__ xq, const __hip_bfloat16* __restrict__ xk,
    const __hip_bfloat16* __restrict__ xv,
    const __hip_bfloat16* __restrict__ Wqt, const __hip_bfloat16* __restrict__ Wkt,
    const __hip_bfloat16* __restrict__ Wvt,
    const float* __restrict__ bq, const float* __restrict__ bk, const float* __restrict__ bv,
    __hip_bfloat16* __restrict__ qb, __hip_bfloat16* __restrict__ kbuf,
    __hip_bfloat16* __restrict__ vtb)
{
    __shared__ __align__(16) __hip_bfloat16 As[2][128 * 32];
    __shared__ __align__(16) __hip_bfloat16 Bs[2][128 * 32];
    const int z = blockIdx.z;
    const __hip_bfloat16* A  = z == 0 ? xq : z == 1 ? xk : xv;
    const __hip_bfloat16* Bt = z == 0 ? Wqt : z == 1 ? Wkt : Wvt;
    const float* bias        = z == 0 ? bq : z == 1 ? bk : bv;
    void* out                = z == 0 ? (void*)qb : z == 1 ? (void*)kbuf : (void*)vtb;
    gemm_body(A, Bt, bias, out, z == 2 ? 1 : 0, As, Bs, blockIdx.x * 128, blockIdx.y * 128);
}

__global__ __launch_bounds__(256, 2) void gemm_wo(
    const __hip_bfloat16* __restrict__ A, const __hip_bfloat16* __restrict__ Bt,
    const float* __restrict__ bias, float* __restrict__ Cout)
{
    __shared__ __align__(16) __hip_bfloat16 As[2][128 * 32];
    __shared__ __align__(16) __hip_bfloat16 Bs[2][128 * 32];
    gemm_body(A, Bt, bias, (void*)Cout, 2, As, Bs, blockIdx.x * 128, blockIdx.y * 128);
}

// ---------------------------------------------------------------------------
// Fused attention, 2-pass flash with 2-phase double-buffered staging.
// pass1: l = sum_k exp(s*scale)  (scores bounded, no max-subtraction)
// pass2: recompute s, w = exp(s*scale)/l -> nontemporal f32 store (d_out),
//        P routed through wave-local swizzled LDS -> PV MFMA accumulate.
// K/V/P LDS rows XOR-swizzled (byte ^= (row&7)<<4); swizzle applied on the
// *global source* address for global_load_lds (linear LDS dest, rule #21).
__global__ __launch_bounds__(256, 2) void attn_fused(
    const __hip_bfloat16* __restrict__ qb,   // [B,H,S,64]
    const __hip_bfloat16* __restrict__ kb,   // [B,H,S,64]
    const __hip_bfloat16* __restrict__ vt,   // [B,H,64,S]
    float* __restrict__ attnw,               // [B,H,S,S]
    __hip_bfloat16* __restrict__ aout)       // [B,S,H*64]
{
    __shared__ __align__(16) __hip_bfloat16 ks_[2][64 * 64];
    __shared__ __align__(16) __hip_bfloat16 vs_[2][64 * 64];
    __shared__ __align__(16) __hip_bfloat16 ps_[128 * 64];

    // XCD-chunked swizzle: dispatch round-robins wg%8 across XCDs; give each
    // XCD 64 contiguous (bh,qt) units -> each head's K/V fetched on one XCD.
    const int wg  = blockIdx.x;              // 0..511
    const int lin = (wg & 7) * 64 + (wg >> 3);
    const int bh  = lin >> 4;                // b*16+h
    const int qt  = lin & 15;                // q tile 0..15

    const int tid = threadIdx.x, wid = tid >> 6, lane = tid & 63;
    const int qrow0 = qt * 128 + wid * 32;   // wave's first q row (s index)

    const char* kh = (const char*)(kb + (size_t)bh * S_ * HD_);   // head base
    const char* vh = (const char*)(vt + (size_t)bh * HD_ * S_);

    // Q fragments in registers: rows qrow0 + rf*16 + (lane&15)
    bfx8 qf[2][2];
#pragma unroll
    for (int rf = 0; rf < 2; ++rf)
#pragma unroll
        for (int kx = 0; kx < 2; ++kx)
            qf[rf][kx] = *(const bfx8*)(qb + ((size_t)bh * S_ + qrow0 + rf * 16 + (lane & 15)) * HD_
                                         + kx * 32 + (lane >> 4) * 8);

    const int sr = lane >> 3;   // row within 8-row staging chunk
    const int sc = lane & 7;    // 16B unit within 128B row

    auto stageK = [&](int kt, int buf) {
#pragma unroll
        for (int i = 0; i < 2; ++i) {
            const int rb = wid * 16 + i * 8;
            const int row = rb + sr;
            const int colb = (sc * 16) ^ ((row & 7) << 4);
            gld_lds16(kh + (size_t)(kt * 64 + row) * 128 + colb, (char*)ks_[buf] + rb * 128);
        }
    };
    auto stageV = [&](int kt, int buf) {
#pragma unroll
        for (int i = 0; i < 2; ++i) {
            const int rb = wid * 16 + i * 8;
            const int row = rb + sr;
            const int colb = (sc * 16) ^ ((row & 7) << 4);
            gld_lds16(vh + ((size_t)row * S_ + kt * 64) * 2 + colb, (char*)vs_[buf] + rb * 128);
        }
    };

    // ---------------- pass 1: denominators ----------------
    float lsum[2][4] = {};
    stageK(0, 0);
    __syncthreads();
    for (int kt = 0; kt < 32; ++kt) {
        const int cur = kt & 1;
        if (kt < 31) stageK(kt + 1, cur ^ 1);
        f32x4 c[2][4] = {};
#pragma unroll
        for (int kx = 0; kx < 2; ++kx) {
            bfx8 bfv[4];
#pragma unroll
            for (int cf = 0; cf < 4; ++cf) {
                const int row = cf * 16 + (lane & 15);
                bfv[cf] = *(const bfx8*)((const char*)ks_[cur] + row * 128
                                          + ((kx * 64 + (lane >> 4) * 16) ^ ((row & 7) << 4)));
            }
#pragma unroll
            for (int rf = 0; rf < 2; ++rf)
#pragma unroll
                for (int cf = 0; cf < 4; ++cf)
                    c[rf][cf] = __builtin_amdgcn_mfma_f32_16x16x32_bf16(qf[rf][kx], bfv[cf], c[rf][cf], 0, 0, 0);
        }
#pragma unroll
        for (int rf = 0; rf < 2; ++rf)
#pragma unroll
            for (int r = 0; r < 4; ++r) {
                float s = 0.f;
#pragma unroll
                for (int cf = 0; cf < 4; ++cf) s += __expf(c[rf][cf][r] * SCALE_);
                s += __shfl_xor(s, 1); s += __shfl_xor(s, 2);
                s += __shfl_xor(s, 4); s += __shfl_xor(s, 8);
                lsum[rf][r] += s;
            }
        __syncthreads();
    }
    float linv[2][4];
#pragma unroll
    for (int rf = 0; rf < 2; ++rf)
#pragma unroll
        for (int r = 0; r < 4; ++r) linv[rf][r] = 1.f / lsum[rf][r];

    // ---------------- pass 2: weights + PV ----------------
    f32x4 o[2][4] = {};
    stageK(0, 0);
    stageV(0, 0);
    __syncthreads();
    for (int kt = 0; kt < 32; ++kt) {
        const int cur = kt & 1;
        if (kt < 31) { stageK(kt + 1, cur ^ 1); stageV(kt + 1, cur ^ 1); }

        f32x4 c[2][4] = {};
#pragma unroll
        for (int kx = 0; kx < 2; ++kx) {
            bfx8 bfv[4];
#pragma unroll
            for (int cf = 0; cf < 4; ++cf) {
                const int row = cf * 16 + (lane & 15);
                bfv[cf] = *(const bfx8*)((const char*)ks_[cur] + row * 128
                                          + ((kx * 64 + (lane >> 4) * 16) ^ ((row & 7) << 4)));
            }
#pragma unroll
            for (int rf = 0; rf < 2; ++rf)
#pragma unroll
                for (int cf = 0; cf < 4; ++cf)
                    c[rf][cf] = __builtin_amdgcn_mfma_f32_16x16x32_bf16(qf[rf][kx], bfv[cf], c[rf][cf], 0, 0, 0);
        }

        // normalized weights -> global (nontemporal) + wave-local swizzled LDS
#pragma unroll
        for (int rf = 0; rf < 2; ++rf)
#pragma unroll
            for (int r = 0; r < 4; ++r) {
                const int qrow = qrow0 + rf * 16 + ((lane >> 4) << 2) + r;
                float* wout = attnw + ((size_t)bh * S_ + qrow) * S_ + kt * 64;
                const int prow = wid * 32 + rf * 16 + ((lane >> 4) << 2) + r;
#pragma unroll
                for (int cf = 0; cf < 4; ++cf) {
                    const float w = __expf(c[rf][cf][r] * SCALE_) * linv[rf][r];
                    __builtin_nontemporal_store(w, wout + cf * 16 + (lane & 15));
                    const int pcolb = ((cf * 16 + (lane & 15)) * 2) ^ ((prow & 7) << 4);
                    *(__hip_bfloat16*)((char*)ps_ + prow * 128 + pcolb) = __float2bfloat16(w);
                }
            }

        // O += P @ V   (P rows are wave-local: no barrier, lgkmcnt ordering only)
#pragma unroll
        for (int kx = 0; kx < 2; ++kx) {
            bfx8 pf[2], vf[4];
#pragma unroll
            for (int rf = 0; rf < 2; ++rf) {
                const int prow = wid * 32 + rf * 16 + (lane & 15);
                pf[rf] = *(const bfx8*)((const char*)ps_ + prow * 128
                                         + ((kx * 64 + (lane >> 4) * 16) ^ ((prow & 7) << 4)));
            }
#pragma unroll
            for (int df = 0; df < 4; ++df) {
                const int vrow = df * 16 + (lane & 15);
                vf[df] = *(const bfx8*)((const char*)vs_[cur] + vrow * 128
                                         + ((kx * 64 + (lane >> 4) * 16) ^ ((vrow & 7) << 4)));
            }
#pragma unroll
            for (int rf = 0; rf < 2; ++rf)
#pragma unroll
                for (int df = 0; df < 4; ++df)
                    o[rf][df] = __builtin_amdgcn_mfma_f32_16x16x32_bf16(pf[rf], vf[df], o[rf][df], 0, 0, 0);
        }
        __syncthreads();
    }

    // write attention output (bf16) at [B,S,H*64] for the final GEMM
    const int b = bh >> 4, h = bh & 15;
#pragma unroll
    for (int rf = 0; rf < 2; ++rf)
#pragma unroll
        for (int r = 0; r < 4; ++r) {
            const int s = qrow0 + rf * 16 + ((lane >> 4) << 2) + r;
#pragma unroll
            for (int df = 0; df < 4; ++df) {
                const int d = df * 16 + (lane & 15);
                aout[((size_t)b * S_ + s) * D_ + h * HD_ + d] = __float2bfloat16(o[rf][df][r]);
            }
        }
}

// ---------------------------------------------------------------------------
extern "C" void kernel_launch(void* const* d_in, const int* in_sizes, int n_in,
                              void* d_out, int out_size, void* d_ws, size_t ws_size,
                              hipStream_t stream)
{
    (void)in_sizes; (void)n_in; (void)out_size; (void)ws_size;
    const float* query = (const float*)d_in[0];
    const float* key_  = (const float*)d_in[1];
    const float* value = (const float*)d_in[2];
    const float* Wq = (const float*)d_in[3];
    const float* bq = (const float*)d_in[4];
    const float* Wk = (const float*)d_in[5];
    const float* bk = (const float*)d_in[6];
    const float* Wv = (const float*)d_in[7];
    const float* bv = (const float*)d_in[8];
    const float* Wo = (const float*)d_in[9];
    const float* bo = (const float*)d_in[10];

    char* ws = (char*)d_ws;
    const size_t MB = 1u << 20;
    __hip_bfloat16* xq   = (__hip_bfloat16*)(ws + 0 * MB);
    __hip_bfloat16* xk   = (__hip_bfloat16*)(ws + 8 * MB);
    __hip_bfloat16* xv   = (__hip_bfloat16*)(ws + 16 * MB);
    __hip_bfloat16* Wqt  = (__hip_bfloat16*)(ws + 24 * MB);
    __hip_bfloat16* Wkt  = (__hip_bfloat16*)(ws + 26 * MB);
    __hip_bfloat16* Wvt  = (__hip_bfloat16*)(ws + 28 * MB);
    __hip_bfloat16* Wot  = (__hip_bfloat16*)(ws + 30 * MB);
    __hip_bfloat16* qb   = (__hip_bfloat16*)(ws + 32 * MB);
    __hip_bfloat16* kbuf = (__hip_bfloat16*)(ws + 40 * MB);
    __hip_bfloat16* vtb  = (__hip_bfloat16*)(ws + 48 * MB);
    __hip_bfloat16* aout = (__hip_bfloat16*)(ws + 56 * MB);

    float* outp  = (float*)d_out;
    float* attnw = outp + (size_t)B_ * S_ * D_;

    cast3_bf16<<<dim3(4096, 3), 256, 0, stream>>>(query, key_, value, xq, xk, xv);
    transpose_cast_w<<<dim3(32, 32, 4), dim3(32, 8), 0, stream>>>(Wq, Wk, Wv, Wo, Wqt, Wkt, Wvt, Wot);
    gemm_qkv<<<dim3(32, 8, 3), 256, 0, stream>>>(xq, xk, xv, Wqt, Wkt, Wvt, bq, bk, bv, qb, kbuf, vtb);
    attn_fused<<<dim3(512), 256, 0, stream>>>(qb, kbuf, vtb, attnw, aout);
    gemm_wo<<<dim3(32, 8), 256, 0, stream>>>(aout, Wot, bo, outp);
}